// Round 1
// baseline (1725.199 us; speedup 1.0000x reference)
//
#include <hip/hip_runtime.h>
#include <hip/hip_bf16.h>

// MultiHeadAttentionCell: B=2, L=2048, H=16, C=64, fp32 in/out.
// Outputs (concat in d_out): context_vec (B,L,H*C)=4194304 | scores (B,H,L,L)=134217728 | attn (B,H,L,L)=134217728
// scores = Q K^T + edge ; attn = softmax(where(mask, scores/8, -1e18)) * mask ; ctx = attn @ V

typedef __attribute__((ext_vector_type(8))) short bf16x8;  // 8 bf16 = 4 VGPRs
typedef __attribute__((ext_vector_type(4))) float f32x4;

#define LQ 2048
#define NH 16
#define CD 64

__device__ inline short f2bf(float x) {
    union { float f; unsigned u; } v; v.f = x;
    unsigned r = v.u + 0x7FFFu + ((v.u >> 16) & 1u);   // RTNE
    return (short)(r >> 16);
}

__device__ inline float wave_max(float v) {
    #pragma unroll
    for (int o = 32; o > 0; o >>= 1) v = fmaxf(v, __shfl_xor(v, o, 64));
    return v;
}
__device__ inline float wave_sum(float v) {
    #pragma unroll
    for (int o = 32; o > 0; o >>= 1) v += __shfl_xor(v, o, 64);
    return v;
}

// ---------------- Kernel 1: scores = Q K^T + edge -------------------------
// grid: (32 j-tiles, 32 i-tiles, 32 z=h*2+b), block 256 (4 waves).
// Block computes a 64x64 tile; each wave 16 rows x 64 cols (4 MFMA tiles).
__global__ __launch_bounds__(256)
void k_scores(const float* __restrict__ q, const float* __restrict__ kk,
              const float* __restrict__ edge, float* __restrict__ sc)
{
    __shared__ short Qs[64][72];   // pad to 72 bf16 (36 dw): 2-way bank aliasing = free
    __shared__ short Ks[64][72];
    const int z = blockIdx.z;
    const int b = z & 1, h = z >> 1;              // z = h*2+b: both b's of same h adjacent -> edge L2/L3 reuse
    const int i0 = blockIdx.y * 64, j0 = blockIdx.x * 64;
    const int tid = threadIdx.x;
    const int r = tid >> 2, seg = (tid & 3) * 16; // thread stages 16 floats of one row

    const float* qrow = q  + ((size_t)((b * LQ + i0 + r) * NH + h)) * CD + seg;
    const float* krow = kk + ((size_t)((b * LQ + j0 + r) * NH + h)) * CD + seg;
    #pragma unroll
    for (int u = 0; u < 4; ++u) {
        float4 f = ((const float4*)qrow)[u];
        *(short4*)&Qs[r][seg + u * 4] = make_short4(f2bf(f.x), f2bf(f.y), f2bf(f.z), f2bf(f.w));
        float4 g = ((const float4*)krow)[u];
        *(short4*)&Ks[r][seg + u * 4] = make_short4(f2bf(g.x), f2bf(g.y), f2bf(g.z), f2bf(g.w));
    }
    __syncthreads();

    const int wave = tid >> 6, lane = tid & 63;
    const int quad = lane >> 4, mm = lane & 15;

    // A fragment: A[m=lane&15][k=quad*8+j]
    bf16x8 a0 = *(const bf16x8*)&Qs[wave * 16 + mm][quad * 8];
    bf16x8 a1 = *(const bf16x8*)&Qs[wave * 16 + mm][32 + quad * 8];

    f32x4 acc[4];
    #pragma unroll
    for (int jt = 0; jt < 4; ++jt) {
        // B fragment: B[k=quad*8+j][n=lane&15] = K[j0+jt*16+n][k]
        bf16x8 b0 = *(const bf16x8*)&Ks[jt * 16 + mm][quad * 8];
        bf16x8 b1 = *(const bf16x8*)&Ks[jt * 16 + mm][32 + quad * 8];
        f32x4 a = {0.f, 0.f, 0.f, 0.f};
        a = __builtin_amdgcn_mfma_f32_16x16x32_bf16(a0, b0, a, 0, 0, 0);
        a = __builtin_amdgcn_mfma_f32_16x16x32_bf16(a1, b1, a, 0, 0, 0);
        acc[jt] = a;
    }

    // C/D layout: col = lane&15, row = quad*4 + reg
    const int irow = i0 + wave * 16 + quad * 4;
    #pragma unroll
    for (int jt = 0; jt < 4; ++jt) {
        const int j = j0 + jt * 16 + mm;
        #pragma unroll
        for (int reg = 0; reg < 4; ++reg) {
            const int i = irow + reg;
            const size_t eidx = ((size_t)(h * LQ + i)) * LQ + j;
            const size_t sidx = ((size_t)((b * NH + h) * LQ + i)) * LQ + j;
            sc[sidx] = acc[jt][reg] + edge[eidx];
        }
    }
}

// ---------------- Kernel 2: masked softmax -------------------------------
// One wave per row (2048 elems, 32/lane, all in registers). 4 waves/block.
__global__ __launch_bounds__(256)
void k_softmax(const float* __restrict__ sc, const int* __restrict__ mask,
               float* __restrict__ attn)
{
    const int wave = threadIdx.x >> 6, lane = threadIdx.x & 63;
    const int gw = blockIdx.x * 4 + wave;          // row id = bh*2048 + i
    const int bh = gw >> 11;
    const int i  = gw & 2047;
    const int b  = bh >> 4;

    const float* srow = sc + (size_t)gw * LQ;
    const int*   mrow = mask + ((size_t)(b * LQ + i)) * LQ;

    float sv[32];
    float vmax = -3.0e38f;
    #pragma unroll
    for (int t = 0; t < 8; ++t) {
        const int j = t * 256 + lane * 4;
        float4 s = *(const float4*)(srow + j);
        int4   m = *(const int4*)(mrow + j);
        sv[t * 4 + 0] = m.x ? s.x * 0.125f : -1.0e18f;
        sv[t * 4 + 1] = m.y ? s.y * 0.125f : -1.0e18f;
        sv[t * 4 + 2] = m.z ? s.z * 0.125f : -1.0e18f;
        sv[t * 4 + 3] = m.w ? s.w * 0.125f : -1.0e18f;
        vmax = fmaxf(vmax, fmaxf(fmaxf(sv[t*4], sv[t*4+1]), fmaxf(sv[t*4+2], sv[t*4+3])));
    }
    vmax = wave_max(vmax);

    float psum = 0.f;
    #pragma unroll
    for (int t = 0; t < 32; ++t) {
        sv[t] = __expf(sv[t] - vmax);   // masked: exp(-1e18 - vmax) == 0
        psum += sv[t];
    }
    psum = wave_sum(psum);
    // all-masked row: vmax == -1e18, every p==1 -> w would be 1/2048; ref multiplies by mask -> 0
    const float inv = (vmax < -9.0e17f) ? 0.f : 1.f / psum;

    float* arow = attn + (size_t)gw * LQ;
    #pragma unroll
    for (int t = 0; t < 8; ++t) {
        float4 o;
        o.x = sv[t*4+0] * inv; o.y = sv[t*4+1] * inv;
        o.z = sv[t*4+2] * inv; o.w = sv[t*4+3] * inv;
        *(float4*)(arow + t * 256 + lane * 4) = o;
    }
}

// ---------------- Kernel 3: ctx = attn @ V -------------------------------
// grid: (32 i-tiles, 32 y=h*2+b), block 256. M-tile 64, N=64 (full C), K-chunks of 64.
__global__ __launch_bounds__(256)
void k_pv(const float* __restrict__ attn, const float* __restrict__ v,
          float* __restrict__ out0)
{
    __shared__ short Ws[64][72];   // W[i_local][j_local] bf16
    __shared__ short Vt[64][72];   // V^T: Vt[c][j_local] bf16
    const int y = blockIdx.y;
    const int b = y & 1, h = y >> 1;
    const int i0 = blockIdx.x * 64;
    const int tid = threadIdx.x;
    const int r = tid >> 2, seg = (tid & 3) * 16;
    const int wave = tid >> 6, lane = tid & 63;
    const int quad = lane >> 4, mm = lane & 15;
    const int bh = b * NH + h;

    f32x4 acc[4] = { {0,0,0,0}, {0,0,0,0}, {0,0,0,0}, {0,0,0,0} };

    for (int kb = 0; kb < 32; ++kb) {
        const int j0 = kb * 64;
        const float* wrow = attn + ((size_t)(bh * LQ + i0 + r)) * LQ + j0 + seg;
        const float* vrow = v + ((size_t)((b * LQ + j0 + r) * NH + h)) * CD + seg;
        #pragma unroll
        for (int u = 0; u < 4; ++u) {
            float4 f = ((const float4*)wrow)[u];
            *(short4*)&Ws[r][seg + u * 4] = make_short4(f2bf(f.x), f2bf(f.y), f2bf(f.z), f2bf(f.w));
            float4 g = ((const float4*)vrow)[u];
            Vt[seg + u * 4 + 0][r] = f2bf(g.x);
            Vt[seg + u * 4 + 1][r] = f2bf(g.y);
            Vt[seg + u * 4 + 2][r] = f2bf(g.z);
            Vt[seg + u * 4 + 3][r] = f2bf(g.w);
        }
        __syncthreads();

        #pragma unroll
        for (int kt = 0; kt < 2; ++kt) {
            bf16x8 a = *(const bf16x8*)&Ws[wave * 16 + mm][kt * 32 + quad * 8];
            #pragma unroll
            for (int nt = 0; nt < 4; ++nt) {
                bf16x8 bb = *(const bf16x8*)&Vt[nt * 16 + mm][kt * 32 + quad * 8];
                acc[nt] = __builtin_amdgcn_mfma_f32_16x16x32_bf16(a, bb, acc[nt], 0, 0, 0);
            }
        }
        __syncthreads();
    }

    const int irow = i0 + wave * 16 + quad * 4;
    #pragma unroll
    for (int nt = 0; nt < 4; ++nt) {
        const int c = nt * 16 + mm;
        #pragma unroll
        for (int reg = 0; reg < 4; ++reg) {
            const int i = irow + reg;
            out0[((size_t)(b * LQ + i)) * (NH * CD) + h * CD + c] = acc[nt][reg];
        }
    }
}

extern "C" void kernel_launch(void* const* d_in, const int* in_sizes, int n_in,
                              void* d_out, int out_size, void* d_ws, size_t ws_size,
                              hipStream_t stream) {
    const float* q    = (const float*)d_in[0];
    const float* k    = (const float*)d_in[1];
    const float* v    = (const float*)d_in[2];
    const int*   mask = (const int*)d_in[3];    // bool -> int32 per harness contract
    const float* edge = (const float*)d_in[4];

    float* out = (float*)d_out;
    float* ctx = out;                            // 2*2048*1024
    float* sc  = out + 4194304;                  // scores (B,H,L,L)
    float* at  = sc + 134217728;                 // attn   (B,H,L,L)

    k_scores <<<dim3(32, 32, 32), 256, 0, stream>>>(q, k, edge, sc);
    k_softmax<<<dim3(16384), 256, 0, stream>>>(sc, mask, at);
    k_pv     <<<dim3(32, 32), 256, 0, stream>>>(at, v, ctx);
}